// Round 11
// baseline (2839.536 us; speedup 1.0000x reference)
//
#include <hip/hip_runtime.h>
#include <stdint.h>

// Problem constants
#define B_  64
#define S_  512
#define D_  1024
#define H_  1024

// Stage-2 partitioning: 4 row-groups (16 batch rows) x 32 col-blocks (32 cols)
#define NBLK2 128

typedef __attribute__((ext_vector_type(2))) float    f32x2;
typedef __attribute__((ext_vector_type(4))) float    f32x4;
typedef __attribute__((ext_vector_type(4))) uint32_t u32x4;
typedef __attribute__((ext_vector_type(8))) __bf16   bf16x8;

__device__ __forceinline__ f32x4 mfma16(bf16x8 a, bf16x8 b, f32x4 c) {
  return __builtin_amdgcn_mfma_f32_16x16x32_bf16(a, b, c, 0, 0, 0);
}

__device__ __forceinline__ void gload_lds16(const void* g, void* l) {
  __builtin_amdgcn_global_load_lds(
      (const __attribute__((address_space(1))) void*)g,
      (__attribute__((address_space(3))) void*)l, 16, 0, 0);
}

// ---- MALL-coherent (cross-XCD) access helpers: sc0 sc1 = bypass L1/L2 ----
__device__ __forceinline__ void st_dword_sc(uint32_t* p, uint32_t v) {
  asm volatile("global_store_dword %0, %1, off sc0 sc1" :: "v"(p), "v"(v) : "memory");
}
__device__ __forceinline__ uint32_t ld_dword_sc(const uint32_t* p) {
  uint32_t r;
  asm volatile("global_load_dword %0, %1, off sc0 sc1\n\t"
               "s_waitcnt vmcnt(0)" : "=v"(r) : "v"(p) : "memory");
  return r;
}
// issue-only 16B coherent load; caller must s_waitcnt vmcnt(0) before use
__device__ __forceinline__ void ld_dwordx4_sc_issue(u32x4& dst, const void* p) {
  asm volatile("global_load_dwordx4 %0, %1, off sc0 sc1" : "=v"(dst) : "v"(p));
}

// pack hi16 halves of two u32 (a -> high half of result)
__device__ __forceinline__ uint32_t permhi(uint32_t a, uint32_t b) {
  return __builtin_amdgcn_perm(a, b, 0x07060302u);
}

// fast tanh: |err| ~1e-6, no libcall
__device__ __forceinline__ float tanh_fast(float x) {
  float ax = fabsf(x);
  float e = __expf(-2.0f * ax);          // (0, 1]
  float r = (1.0f - e) / (1.0f + e);     // tanh(|x|) in [0,1)
  return x < 0.0f ? -r : r;
}

// 8 fp32 -> (hi, lo) bf16x8 via truncation split (stage-1 helper)
__device__ __forceinline__ void split8(f32x4 a0, f32x4 a1, bf16x8& hi, bf16x8& lo) {
  float f[8] = {a0.x, a0.y, a0.z, a0.w, a1.x, a1.y, a1.z, a1.w};
  uint32_t hb[8], lb[8];
#pragma unroll
  for (int i = 0; i < 8; ++i) {
    uint32_t b = __builtin_bit_cast(uint32_t, f[i]);
    hb[i] = b;
    float hf = __builtin_bit_cast(float, b & 0xffff0000u);
    lb[i] = __builtin_bit_cast(uint32_t, f[i] - hf);
  }
  u32x4 hv = {permhi(hb[1], hb[0]), permhi(hb[3], hb[2]),
              permhi(hb[5], hb[4]), permhi(hb[7], hb[6])};
  u32x4 lv = {permhi(lb[1], lb[0]), permhi(lb[3], lb[2]),
              permhi(lb[5], lb[4]), permhi(lb[7], lb[6])};
  hi = __builtin_bit_cast(bf16x8, hv);
  lo = __builtin_bit_cast(bf16x8, lv);
}

// ---------------------------------------------------------------------------
// prep: WxT/WhT = transpose + hi/lo bf16 split of Wx, Wh ([n][k] layout).
// Re-init: all hq tags to 0xFFFF, all flags to 0 (replay-safe each launch).
// ---------------------------------------------------------------------------
__global__ __launch_bounds__(256) void prep_kernel(
    const float* __restrict__ Wx, const float* __restrict__ Wh,
    uint16_t* __restrict__ wxt_hi, uint16_t* __restrict__ wxt_lo,
    uint16_t* __restrict__ wht_hi, uint16_t* __restrict__ wht_lo,
    uint32_t* __restrict__ hq, unsigned* __restrict__ flags)
{
  {
    int gid = blockIdx.x * 256 + threadIdx.x;
    if (gid < 2 * 64 * 1024) hq[gid] = 0xFFFFFFFFu;   // tag never matches t<=510
  }
  if (blockIdx.x == 0) {
    for (int i = threadIdx.x; i < 1024; i += 256)
      st_dword_sc((uint32_t*)flags + i, 0u);
  }
  __shared__ float tile[32][33];
  int bid = blockIdx.x;
  int mat = bid >> 10;
  int t   = bid & 1023;
  int tk = t >> 5, tn = t & 31;
  const float* src = mat ? Wh : Wx;
  uint16_t* dhi = mat ? wht_hi : wxt_hi;
  uint16_t* dlo = mat ? wht_lo : wxt_lo;
  int tx = threadIdx.x & 31, ty0 = threadIdx.x >> 5;
  int k0 = tk * 32, n0 = tn * 32;
#pragma unroll
  for (int i = 0; i < 4; ++i) {
    int ty = ty0 + 8 * i;
    tile[ty][tx] = src[(size_t)(k0 + ty) * 1024 + n0 + tx];
  }
  __syncthreads();
#pragma unroll
  for (int i = 0; i < 4; ++i) {
    int ty = ty0 + 8 * i;
    float v = tile[tx][ty];                 // = src[k0+tx][n0+ty]
    uint32_t bv = __builtin_bit_cast(uint32_t, v);
    float lo = v - __builtin_bit_cast(float, bv & 0xffff0000u);
    uint32_t lbv = __builtin_bit_cast(uint32_t, lo);
    size_t o = (size_t)(n0 + ty) * 1024 + k0 + tx;   // [n][k]
    dhi[o] = (uint16_t)(bv >> 16);
    dlo[o] = (uint16_t)(lbv >> 16);
  }
}

// ---------------------------------------------------------------------------
// stage 1: out[b*512+s][h] = x @ Wx + b   (split-bf16, 3 terms)  — unchanged
// ---------------------------------------------------------------------------
__global__ __launch_bounds__(256) void xw_gemm_kernel(
    const float* __restrict__ x, const uint16_t* __restrict__ wxt_hi,
    const uint16_t* __restrict__ wxt_lo, const float* __restrict__ bias,
    float* __restrict__ out)
{
  __shared__ __align__(16) float    ldsA[128 * 32];
  __shared__ __align__(16) uint16_t ldsBh[128 * 32];
  __shared__ __align__(16) uint16_t ldsBl[128 * 32];

  int bid = blockIdx.x;
  int swz = (bid & 7) * 256 + (bid >> 3);     // XCD-aware (2048 % 8 == 0)
  int mt = swz >> 3, nt = swz & 7;
  int M0 = mt * 128, N0 = nt * 128;

  int tid = threadIdx.x;
  int w = tid >> 6, l = tid & 63;
  int wm = w >> 1, wn = w & 1;

  int a_row = l >> 3;
  int a_sw  = ((l & 7) ^ (l >> 3)) << 4;
  int b_row = l >> 2;
  int b_sw  = (((l & 3) ^ ((l >> 2) & 3)) << 4);

  f32x4 acc[4][4];
#pragma unroll
  for (int i = 0; i < 4; ++i)
#pragma unroll
    for (int j = 0; j < 4; ++j) acc[i][j] = (f32x4){0.f, 0.f, 0.f, 0.f};

  const char* xb  = (const char*)x;
  const char* bhp = (const char*)wxt_hi;
  const char* blp = (const char*)wxt_lo;

  for (int s = 0; s < 32; ++s) {
#pragma unroll
    for (int j = 0; j < 4; ++j) {
      int i = 4 * w + j;
      const char* g = xb + ((size_t)(M0 + 8 * i + a_row) * 4096) + s * 128 + a_sw;
      gload_lds16(g, (char*)ldsA + i * 1024);
    }
#pragma unroll
    for (int j = 0; j < 2; ++j) {
      int i = 2 * w + j;
      size_t ro = (size_t)(N0 + 16 * i + b_row) * 2048 + s * 64 + b_sw;
      gload_lds16(bhp + ro, (char*)ldsBh + i * 1024);
      gload_lds16(blp + ro, (char*)ldsBl + i * 1024);
    }
    __syncthreads();

    bf16x8 ah[4], al[4], bh[4], bl[4];
#pragma unroll
    for (int mi = 0; mi < 4; ++mi) {
      int row = 64 * wm + 16 * mi + (l & 15);
      int kb  = (l >> 4) * 32;
      int sw  = (row & 7) << 4;
      f32x4 a0 = *(const f32x4*)((const char*)ldsA + row * 128 + (kb ^ sw));
      f32x4 a1 = *(const f32x4*)((const char*)ldsA + row * 128 + ((kb + 16) ^ sw));
      split8(a0, a1, ah[mi], al[mi]);
    }
#pragma unroll
    for (int ni = 0; ni < 4; ++ni) {
      int n  = 64 * wn + 16 * ni + (l & 15);
      int kb = (l >> 4) * 16;
      int off = n * 64 + (kb ^ ((n & 3) << 4));
      bh[ni] = *(const bf16x8*)((const char*)ldsBh + off);
      bl[ni] = *(const bf16x8*)((const char*)ldsBl + off);
    }
#pragma unroll
    for (int mi = 0; mi < 4; ++mi)
#pragma unroll
      for (int ni = 0; ni < 4; ++ni) {
        acc[mi][ni] = mfma16(ah[mi], bh[ni], acc[mi][ni]);
        acc[mi][ni] = mfma16(al[mi], bh[ni], acc[mi][ni]);
        acc[mi][ni] = mfma16(ah[mi], bl[ni], acc[mi][ni]);
      }
    __syncthreads();
  }

#pragma unroll
  for (int ni = 0; ni < 4; ++ni) {
    int col = N0 + 64 * wn + 16 * ni + (l & 15);
    float bv = bias[col];
#pragma unroll
    for (int mi = 0; mi < 4; ++mi) {
      int row0 = M0 + 64 * wm + 16 * mi + 4 * (l >> 4);
#pragma unroll
      for (int r = 0; r < 4; ++r)
        out[(size_t)(row0 + r) * 1024 + col] = acc[mi][ni][r] + bv;
    }
  }
}

// ---------------------------------------------------------------------------
// stage 2: persistent sequential recurrence.
// Protocol = R5's cheap per-producer-wave FLAG detect + R6's ACK-FREE tagged
// data. 128 blocks x 512 thr (8 waves). Block (g,c): rows [16g,16g+16),
// cols [32c,32c+32). Wave kw owns k-slice [128kw,+128).
// h element = u32: (RNE bf16 << 16) | (t & 0xffff).
// Producer per wave: tagged sc stores -> flag store IMMEDIATELY (no vmcnt
// ack; flag may beat data) -> out store (plain, cheap L2 ack).
// Consumer wave: (1) sleep-paced poll of its 32 producer-wave flags (128 B /
// iter — no MALL storm); (2) ONE bulk 8x dwordx4 tagged load + validate all
// 32 tags in-register (the correctness gate; catches flag-ahead-of-data
// skew); stale -> sleep-paced re-issue (rare). Parity-dbuf LDS reduce, ONE
// barrier/step. 2-slot h buffer safe: full bipartite dependency bounds
// inter-block skew to 1 step.
// ---------------------------------------------------------------------------
__global__ __launch_bounds__(512, 1) void rnn_seq_kernel(
    float* __restrict__ out,
    const uint16_t* wht_hi, const uint16_t* wht_lo,   // NOT restrict (remat aid)
    uint32_t* __restrict__ hq,                        // 2 x 64 x 1024 tagged u32
    unsigned* __restrict__ flags)                     // [4 g][32 c][8 w]
{
  __shared__ __align__(16) float red[2][8][16][33];   // parity-dbuf, 33.8 KB

  const int bid = blockIdx.x;
  const int g   = bid >> 5;          // row-group 0..3
  const int c   = bid & 31;          // col-block 0..31
  const int c0  = c * 32;

  const int tid = threadIdx.x;
  const int kw  = tid >> 6;          // k-slice 0..7 (128 k each)
  const int l   = tid & 63;
  const int lr  = l & 15, lq = l >> 4;

  // ---- preload Wh slice (compiler-managed; remat ok — R5 measured best) ----
  u32x4 wbh[2][4], wbl[2][4];
#pragma unroll
  for (int n2 = 0; n2 < 2; ++n2) {
    const size_t colb = (size_t)(c0 + n2 * 16 + lr) * 1024 + kw * 128 + lq * 8;
#pragma unroll
    for (int kc = 0; kc < 4; ++kc) {
      wbh[n2][kc] = *(const u32x4*)(wht_hi + colb + kc * 32);
      wbl[n2][kc] = *(const u32x4*)(wht_lo + colb + kc * 32);
    }
  }

  // A-frag source: tagged h row = g*16+lr, k = kw*128 + kc*32 + lq*8
  const uint32_t* hq_base = hq + (size_t)(g * 16 + lr) * 1024 + kw * 128 + lq * 8;
  const int HQ = 64 * 1024;   // u32 elems per slot

  // finalize: 1 output/thread: row = tid>>5 (0..15), col = tid&31 (0..31)
  const int frow = tid >> 5;
  const int fcol = tid & 31;
  const size_t out_base = ((size_t)(g * 16 + frow) * 512) * 1024 + c0 + fcol;
  const size_t h_off    = (size_t)(g * 16 + frow) * 1024 + c0 + fcol;

  // wave kw consumes producers c' = 4kw..4kw+3, waves 0..7 -> 32 flags
  const uint32_t* fpoll = (const uint32_t*)flags + g * 256 + kw * 32 + (l & 31);
  uint32_t*       fown  = (uint32_t*)flags + g * 256 + c * 8 + kw;  // kw == wave

  for (int t = 0; t < 512; ++t) {
    // pin Wh fragments in-loop (forbid hoist-free remat drift; R5 pattern)
#pragma unroll
    for (int n2 = 0; n2 < 2; ++n2)
#pragma unroll
      for (int kc = 0; kc < 4; ++kc) {
        asm volatile("" : "+v"(wbh[n2][kc]));
        asm volatile("" : "+v"(wbl[n2][kc]));
      }

    // prefetch xw_t (1 float/thread; drains under first poll's vmcnt)
    float xwv = out[out_base + (size_t)t * 1024];

    f32x4 cH0 = {0.f,0.f,0.f,0.f}, cL0 = {0.f,0.f,0.f,0.f};
    f32x4 cH1 = {0.f,0.f,0.f,0.f}, cL1 = {0.f,0.f,0.f,0.f};

    if (t > 0) {
      // ---- (1) sleep-paced flag poll: 32 dwords/wave, cheap ----
      const unsigned tgt = (unsigned)t;
      while (true) {
        unsigned v = ld_dword_sc(fpoll);
        if (!__any((int)(v < tgt))) break;
        __builtin_amdgcn_s_sleep(1);
      }

      // ---- (2) bulk tagged loads + validate; sleep-paced rare retry ----
      const uint32_t* hb = hq_base + ((t - 1) & 1) * HQ;
      const uint32_t expect = (uint32_t)(t - 1) & 0xffffu;
      u32x4 pk[4][2];
#pragma unroll
      for (int kc = 0; kc < 4; ++kc) {
        ld_dwordx4_sc_issue(pk[kc][0], hb + kc * 32);
        ld_dwordx4_sc_issue(pk[kc][1], hb + kc * 32 + 4);
      }
      while (true) {
        __builtin_amdgcn_sched_barrier(0);
        asm volatile("s_waitcnt vmcnt(0)" ::: "memory");
        __builtin_amdgcn_sched_barrier(0);
        uint32_t bad = 0;
#pragma unroll
        for (int kc = 0; kc < 4; ++kc)
#pragma unroll
          for (int j = 0; j < 2; ++j)
#pragma unroll
            for (int e = 0; e < 4; ++e)
              bad |= (pk[kc][j][e] ^ expect);
        bad &= 0xffffu;
        if (!__any((int)bad)) break;
        __builtin_amdgcn_s_sleep(1);
#pragma unroll
        for (int kc = 0; kc < 4; ++kc) {
          ld_dwordx4_sc_issue(pk[kc][0], hb + kc * 32);
          ld_dwordx4_sc_issue(pk[kc][1], hb + kc * 32 + 4);
        }
      }

      // ---- unpack hi16 -> bf16 frags, 16 MFMAs (4 chains x 4 deep) ----
#pragma unroll
      for (int kc = 0; kc < 4; ++kc) {
        u32x4 aw;
        aw[0] = permhi(pk[kc][0][1], pk[kc][0][0]);
        aw[1] = permhi(pk[kc][0][3], pk[kc][0][2]);
        aw[2] = permhi(pk[kc][1][1], pk[kc][1][0]);
        aw[3] = permhi(pk[kc][1][3], pk[kc][1][2]);
        bf16x8 a = __builtin_bit_cast(bf16x8, aw);
        cH0 = mfma16(a, __builtin_bit_cast(bf16x8, wbh[0][kc]), cH0);
        cH1 = mfma16(a, __builtin_bit_cast(bf16x8, wbh[1][kc]), cH1);
        cL0 = mfma16(a, __builtin_bit_cast(bf16x8, wbl[0][kc]), cL0);
        cL1 = mfma16(a, __builtin_bit_cast(bf16x8, wbl[1][kc]), cL1);
      }
    }

    f32x4 acc0 = cH0 + cL0;
    f32x4 acc1 = cH1 + cL1;

    // ---- cross-wave k reduce: parity dbuf, ONE barrier/step ----
    const int rbuf = t & 1;
#pragma unroll
    for (int r = 0; r < 4; ++r) {
      red[rbuf][kw][lq * 4 + r][lr]      = acc0[r];
      red[rbuf][kw][lq * 4 + r][16 + lr] = acc1[r];
    }
    __syncthreads();

    float s = 0.f;
#pragma unroll
    for (int wv = 0; wv < 8; ++wv)
      s += red[rbuf][wv][frow][fcol];

    // ---- finalize: tagged publish -> flag (NO ack) -> out store last ----
    float hval = tanh_fast(s + xwv);
    if (t < 511) {
      uint32_t b  = __builtin_bit_cast(uint32_t, hval);
      uint32_t hi = (b + 0x7fffu + ((b >> 16) & 1u)) & 0xffff0000u;  // RNE bf16
      st_dword_sc(hq + (size_t)(t & 1) * HQ + h_off, hi | ((uint32_t)t & 0xffffu));
      if (l == 0) st_dword_sc(fown, (uint32_t)(t + 1));   // no vmcnt between!
    }
    out[out_base + (size_t)t * 1024] = hval;
  }
}

// ---------------------------------------------------------------------------
extern "C" void kernel_launch(void* const* d_in, const int* in_sizes, int n_in,
                              void* d_out, int out_size, void* d_ws, size_t ws_size,
                              hipStream_t stream) {
  const float* x    = (const float*)d_in[0];
  const float* Wx   = (const float*)d_in[1];
  const float* Wh   = (const float*)d_in[2];
  const float* bias = (const float*)d_in[3];
  float* out = (float*)d_out;

  // ws layout (~8.5 MiB): split weights + tagged-h double buffer + flags
  char* ws = (char*)d_ws;
  uint16_t* wxt_hi = (uint16_t*)(ws);
  uint16_t* wxt_lo = (uint16_t*)(ws + (2u << 20));
  uint16_t* wht_hi = (uint16_t*)(ws + (4u << 20));
  uint16_t* wht_lo = (uint16_t*)(ws + (6u << 20));
  uint32_t* hq     = (uint32_t*)(ws + (8u << 20));               // 512 KB
  unsigned* flags  = (unsigned*)(ws + (8u << 20) + (1u << 19));  // 4 KB

  prep_kernel<<<dim3(2048), dim3(256), 0, stream>>>(Wx, Wh, wxt_hi, wxt_lo,
                                                    wht_hi, wht_lo, hq, flags);
  xw_gemm_kernel<<<dim3(2048), dim3(256), 0, stream>>>(x, wxt_hi, wxt_lo, bias, out);
  rnn_seq_kernel<<<dim3(NBLK2), dim3(512), 0, stream>>>(out, wht_hi, wht_lo,
                                                        hq, flags);
}

// Round 14
// 1722.796 us; speedup vs baseline: 1.6482x; 1.6482x over previous
//
#include <hip/hip_runtime.h>
#include <stdint.h>

// Problem constants
#define B_  64
#define S_  512
#define D_  1024
#define H_  1024

// Stage-2 partitioning: 4 row-groups (16 batch rows) x 32 col-blocks (32 cols)
#define NBLK2 128

typedef __attribute__((ext_vector_type(2))) float    f32x2;
typedef __attribute__((ext_vector_type(4))) float    f32x4;
typedef __attribute__((ext_vector_type(4))) uint32_t u32x4;
typedef __attribute__((ext_vector_type(8))) __bf16   bf16x8;

__device__ __forceinline__ f32x4 mfma16(bf16x8 a, bf16x8 b, f32x4 c) {
  return __builtin_amdgcn_mfma_f32_16x16x32_bf16(a, b, c, 0, 0, 0);
}

__device__ __forceinline__ void gload_lds16(const void* g, void* l) {
  __builtin_amdgcn_global_load_lds(
      (const __attribute__((address_space(1))) void*)g,
      (__attribute__((address_space(3))) void*)l, 16, 0, 0);
}

// ---- MALL-coherent (cross-XCD) access helpers: sc0 sc1 = bypass L1/L2 ----
__device__ __forceinline__ void st_dword_sc(uint32_t* p, uint32_t v) {
  asm volatile("global_store_dword %0, %1, off sc0 sc1" :: "v"(p), "v"(v) : "memory");
}
__device__ __forceinline__ void st_short_sc(uint16_t* p, uint32_t v) {
  asm volatile("global_store_short %0, %1, off sc0 sc1" :: "v"(p), "v"(v) : "memory");
}
__device__ __forceinline__ uint32_t ld_dword_sc(const uint32_t* p) {
  uint32_t r;
  asm volatile("global_load_dword %0, %1, off sc0 sc1\n\t"
               "s_waitcnt vmcnt(0)" : "=v"(r) : "v"(p) : "memory");
  return r;
}
// issue-only 16B coherent load; caller must s_waitcnt vmcnt(0) before use
__device__ __forceinline__ void ld_dwordx4_sc_issue(u32x4& dst, const void* p) {
  asm volatile("global_load_dwordx4 %0, %1, off sc0 sc1" : "=v"(dst) : "v"(p));
}

// pack hi16 halves of two u32 (a -> high half of result)
__device__ __forceinline__ uint32_t permhi(uint32_t a, uint32_t b) {
  return __builtin_amdgcn_perm(a, b, 0x07060302u);
}

// fast tanh: |err| ~1e-6, no libcall
__device__ __forceinline__ float tanh_fast(float x) {
  float ax = fabsf(x);
  float e = __expf(-2.0f * ax);          // (0, 1]
  float r = (1.0f - e) / (1.0f + e);     // tanh(|x|) in [0,1)
  return x < 0.0f ? -r : r;
}

// 8 fp32 -> (hi, lo) bf16x8 via truncation split (stage-1 helper)
__device__ __forceinline__ void split8(f32x4 a0, f32x4 a1, bf16x8& hi, bf16x8& lo) {
  float f[8] = {a0.x, a0.y, a0.z, a0.w, a1.x, a1.y, a1.z, a1.w};
  uint32_t hb[8], lb[8];
#pragma unroll
  for (int i = 0; i < 8; ++i) {
    uint32_t b = __builtin_bit_cast(uint32_t, f[i]);
    hb[i] = b;
    float hf = __builtin_bit_cast(float, b & 0xffff0000u);
    lb[i] = __builtin_bit_cast(uint32_t, f[i] - hf);
  }
  u32x4 hv = {permhi(hb[1], hb[0]), permhi(hb[3], hb[2]),
              permhi(hb[5], hb[4]), permhi(hb[7], hb[6])};
  u32x4 lv = {permhi(lb[1], lb[0]), permhi(lb[3], lb[2]),
              permhi(lb[5], lb[4]), permhi(lb[7], lb[6])};
  hi = __builtin_bit_cast(bf16x8, hv);
  lo = __builtin_bit_cast(bf16x8, lv);
}

// ---------------------------------------------------------------------------
// prep: WxT/WhT = transpose + hi/lo bf16 split of Wx, Wh ([n][k]).  Zero flags.
// ---------------------------------------------------------------------------
__global__ __launch_bounds__(256) void prep_kernel(
    const float* __restrict__ Wx, const float* __restrict__ Wh,
    uint16_t* __restrict__ wxt_hi, uint16_t* __restrict__ wxt_lo,
    uint16_t* __restrict__ wht_hi, uint16_t* __restrict__ wht_lo,
    unsigned* __restrict__ flags)
{
  if (blockIdx.x == 0) {
    for (int i = threadIdx.x; i < 1024; i += 256)
      st_dword_sc((uint32_t*)flags + i, 0u);
  }
  __shared__ float tile[32][33];
  int bid = blockIdx.x;
  int mat = bid >> 10;
  int t   = bid & 1023;
  int tk = t >> 5, tn = t & 31;
  const float* src = mat ? Wh : Wx;
  uint16_t* dhi = mat ? wht_hi : wxt_hi;
  uint16_t* dlo = mat ? wht_lo : wxt_lo;
  int tx = threadIdx.x & 31, ty0 = threadIdx.x >> 5;
  int k0 = tk * 32, n0 = tn * 32;
#pragma unroll
  for (int i = 0; i < 4; ++i) {
    int ty = ty0 + 8 * i;
    tile[ty][tx] = src[(size_t)(k0 + ty) * 1024 + n0 + tx];
  }
  __syncthreads();
#pragma unroll
  for (int i = 0; i < 4; ++i) {
    int ty = ty0 + 8 * i;
    float v = tile[tx][ty];                 // = src[k0+tx][n0+ty]
    uint32_t bv = __builtin_bit_cast(uint32_t, v);
    float lo = v - __builtin_bit_cast(float, bv & 0xffff0000u);
    uint32_t lbv = __builtin_bit_cast(uint32_t, lo);
    size_t o = (size_t)(n0 + ty) * 1024 + k0 + tx;   // [n][k]
    dhi[o] = (uint16_t)(bv >> 16);
    dlo[o] = (uint16_t)(lbv >> 16);
  }
}

// ---------------------------------------------------------------------------
// stage 1: out[b*512+s][h] = x @ Wx + b   (split-bf16, 3 terms)
// ---------------------------------------------------------------------------
__global__ __launch_bounds__(256) void xw_gemm_kernel(
    const float* __restrict__ x, const uint16_t* __restrict__ wxt_hi,
    const uint16_t* __restrict__ wxt_lo, const float* __restrict__ bias,
    float* __restrict__ out)
{
  __shared__ __align__(16) float    ldsA[128 * 32];
  __shared__ __align__(16) uint16_t ldsBh[128 * 32];
  __shared__ __align__(16) uint16_t ldsBl[128 * 32];

  int bid = blockIdx.x;
  int swz = (bid & 7) * 256 + (bid >> 3);     // XCD-aware (2048 % 8 == 0)
  int mt = swz >> 3, nt = swz & 7;
  int M0 = mt * 128, N0 = nt * 128;

  int tid = threadIdx.x;
  int w = tid >> 6, l = tid & 63;
  int wm = w >> 1, wn = w & 1;

  int a_row = l >> 3;
  int a_sw  = ((l & 7) ^ (l >> 3)) << 4;
  int b_row = l >> 2;
  int b_sw  = (((l & 3) ^ ((l >> 2) & 3)) << 4);

  f32x4 acc[4][4];
#pragma unroll
  for (int i = 0; i < 4; ++i)
#pragma unroll
    for (int j = 0; j < 4; ++j) acc[i][j] = (f32x4){0.f, 0.f, 0.f, 0.f};

  const char* xb  = (const char*)x;
  const char* bhp = (const char*)wxt_hi;
  const char* blp = (const char*)wxt_lo;

  for (int s = 0; s < 32; ++s) {
#pragma unroll
    for (int j = 0; j < 4; ++j) {
      int i = 4 * w + j;
      const char* g = xb + ((size_t)(M0 + 8 * i + a_row) * 4096) + s * 128 + a_sw;
      gload_lds16(g, (char*)ldsA + i * 1024);
    }
#pragma unroll
    for (int j = 0; j < 2; ++j) {
      int i = 2 * w + j;
      size_t ro = (size_t)(N0 + 16 * i + b_row) * 2048 + s * 64 + b_sw;
      gload_lds16(bhp + ro, (char*)ldsBh + i * 1024);
      gload_lds16(blp + ro, (char*)ldsBl + i * 1024);
    }
    __syncthreads();

    bf16x8 ah[4], al[4], bh[4], bl[4];
#pragma unroll
    for (int mi = 0; mi < 4; ++mi) {
      int row = 64 * wm + 16 * mi + (l & 15);
      int kb  = (l >> 4) * 32;
      int sw  = (row & 7) << 4;
      f32x4 a0 = *(const f32x4*)((const char*)ldsA + row * 128 + (kb ^ sw));
      f32x4 a1 = *(const f32x4*)((const char*)ldsA + row * 128 + ((kb + 16) ^ sw));
      split8(a0, a1, ah[mi], al[mi]);
    }
#pragma unroll
    for (int ni = 0; ni < 4; ++ni) {
      int n  = 64 * wn + 16 * ni + (l & 15);
      int kb = (l >> 4) * 16;
      int off = n * 64 + (kb ^ ((n & 3) << 4));
      bh[ni] = *(const bf16x8*)((const char*)ldsBh + off);
      bl[ni] = *(const bf16x8*)((const char*)ldsBl + off);
    }
#pragma unroll
    for (int mi = 0; mi < 4; ++mi)
#pragma unroll
      for (int ni = 0; ni < 4; ++ni) {
        acc[mi][ni] = mfma16(ah[mi], bh[ni], acc[mi][ni]);
        acc[mi][ni] = mfma16(al[mi], bh[ni], acc[mi][ni]);
        acc[mi][ni] = mfma16(ah[mi], bl[ni], acc[mi][ni]);
      }
    __syncthreads();
  }

#pragma unroll
  for (int ni = 0; ni < 4; ++ni) {
    int col = N0 + 64 * wn + 16 * ni + (l & 15);
    float bv = bias[col];
#pragma unroll
    for (int mi = 0; mi < 4; ++mi) {
      int row0 = M0 + 64 * wm + 16 * mi + 4 * (l >> 4);
#pragma unroll
      for (int r = 0; r < 4; ++r)
        out[(size_t)(row0 + r) * 1024 + col] = acc[mi][ni][r] + bv;
    }
  }
}

// ---------------------------------------------------------------------------
// stage 2: persistent sequential recurrence (R5 protocol — measured best).
// 128 blocks x 512 thr (8 waves). Block (g,c): rows [16g,16g+16), cols
// [32c,32c+32). Wave kw owns k-slice [128kw,+128): Wh = 16 frags = 64 VGPR,
// pinned per-iteration. h transported as RNE-rounded bf16 (2B) via sc0/sc1
// MALL ops; Wh stays hi/lo split (B-side exact). Per-WAVE producer flags:
// wave stores its 2 h-rows, vmcnt-acks, sets its own flag — no 2nd barrier.
// One __syncthreads/step with double-buffered LDS reduce.
// ---------------------------------------------------------------------------
__global__ __launch_bounds__(512, 1) void rnn_seq_kernel(
    float* __restrict__ out,
    const uint16_t* wht_hi, const uint16_t* wht_lo,   // NOT restrict (pin aid)
    uint16_t* __restrict__ hq,                        // bf16 h, 2 x 64 x 1024
    unsigned* __restrict__ flags)                     // [4 g][32 c][8 w]
{
  __shared__ __align__(16) float red[2][8][16][33];   // dbuf x kwave x row x col

  const int bid = blockIdx.x;
  const int g   = bid >> 5;          // row-group 0..3
  const int c   = bid & 31;          // col-block 0..31
  const int c0  = c * 32;

  const int tid = threadIdx.x;
  const int kw  = tid >> 6;          // k-slice 0..7 (128 k each)
  const int l   = tid & 63;
  const int lr  = l & 15, lq = l >> 4;

  // ---- preload Wh slice into registers (16 x u32x4 = 64 VGPR) ----
  u32x4 wbh[2][4], wbl[2][4];
#pragma unroll
  for (int n2 = 0; n2 < 2; ++n2) {
    const size_t colb = (size_t)(c0 + n2 * 16 + lr) * 1024 + kw * 128 + lq * 8;
#pragma unroll
    for (int kc = 0; kc < 4; ++kc) {
      wbh[n2][kc] = *(const u32x4*)(wht_hi + colb + kc * 32);
      wbl[n2][kc] = *(const u32x4*)(wht_lo + colb + kc * 32);
    }
  }

  // A-frag source: bf16 h row = g*16+lr, k = kw*128 + kc*32 + lq*8
  const uint16_t* hb_base = hq + (size_t)(g * 16 + lr) * 1024 + kw * 128 + lq * 8;
  const int HQ = 64 * 1024;   // u16 elems per slot

  // finalize: 1 output/thread: row = tid>>5 (0..15), col = tid&31 (0..31)
  const int frow = tid >> 5;
  const int fcol = tid & 31;
  const size_t out_base = ((size_t)(g * 16 + frow) * 512) * 1024 + c0 + fcol;
  const size_t h_off    = (size_t)(g * 16 + frow) * 1024 + c0 + fcol;

  // wave kw consumes producers c' = 4kw..4kw+3, waves 0..7 -> 32 flags
  const uint32_t* fpoll = (const uint32_t*)flags + g * 256 + kw * 32 + (l & 31);
  uint32_t*       fown  = (uint32_t*)flags + g * 256 + c * 8 + kw;  // kw == wave id

  for (int t = 0; t < 512; ++t) {
    // pin Wh in VGPRs each iteration (forbid remat/spill-reload from memory)
#pragma unroll
    for (int n2 = 0; n2 < 2; ++n2)
#pragma unroll
      for (int kc = 0; kc < 4; ++kc) {
        asm volatile("" : "+v"(wbh[n2][kc]));
        asm volatile("" : "+v"(wbl[n2][kc]));
      }

    // prefetch xw_t (1 float/thread, block-private slice of d_out)
    float xwv = out[out_base + (size_t)t * 1024];

    f32x4 cH0 = {0.f,0.f,0.f,0.f}, cL0 = {0.f,0.f,0.f,0.f};
    f32x4 cH1 = {0.f,0.f,0.f,0.f}, cL1 = {0.f,0.f,0.f,0.f};

    if (t > 0) {
      // wait for the 32 per-wave producer flags of this k-slice
      const unsigned tgt = (unsigned)t;
      while (true) {
        unsigned v = ld_dword_sc(fpoll);
        if (!__any((int)(v < tgt))) break;
        __builtin_amdgcn_s_sleep(1);
      }
      // coherent bf16 h loads (4 x dwordx4), one wait
      const uint16_t* hb = hb_base + ((t - 1) & 1) * HQ;
      u32x4 av[4];
#pragma unroll
      for (int kc = 0; kc < 4; ++kc)
        ld_dwordx4_sc_issue(av[kc], hb + kc * 32);
      __builtin_amdgcn_sched_barrier(0);
      asm volatile("s_waitcnt vmcnt(0)" ::: "memory");
      __builtin_amdgcn_sched_barrier(0);
      // 16 MFMAs, 4 independent chains x 4 deep
#pragma unroll
      for (int kc = 0; kc < 4; ++kc) {
        bf16x8 a   = __builtin_bit_cast(bf16x8, av[kc]);
        cH0 = mfma16(a, __builtin_bit_cast(bf16x8, wbh[0][kc]), cH0);
        cH1 = mfma16(a, __builtin_bit_cast(bf16x8, wbh[1][kc]), cH1);
        cL0 = mfma16(a, __builtin_bit_cast(bf16x8, wbl[0][kc]), cL0);
        cL1 = mfma16(a, __builtin_bit_cast(bf16x8, wbl[1][kc]), cL1);
      }
    }

    f32x4 acc0 = cH0 + cL0;
    f32x4 acc1 = cH1 + cL1;

    // ---- cross-wave k reduce (double-buffered; ONE barrier per step) ----
    const int rbuf = t & 1;
#pragma unroll
    for (int r = 0; r < 4; ++r) {
      red[rbuf][kw][lq * 4 + r][lr]      = acc0[r];
      red[rbuf][kw][lq * 4 + r][16 + lr] = acc1[r];
    }
    __syncthreads();

    float s = 0.f;
#pragma unroll
    for (int wv = 0; wv < 8; ++wv)
      s += red[rbuf][wv][frow][fcol];

    // ---- finalize: 1 value/thread ----
    float hval = tanh_fast(s + xwv);
    out[out_base + (size_t)t * 1024] = hval;

    if (t < 511) {
      // RNE round to bf16, publish, ack, per-wave flag
      uint32_t b  = __builtin_bit_cast(uint32_t, hval);
      uint32_t rb = (b + 0x7fffu + ((b >> 16) & 1u)) >> 16;
      st_short_sc(hq + (size_t)(t & 1) * HQ + h_off, rb);
      asm volatile("s_waitcnt vmcnt(0)" ::: "memory");  // h at MALL before flag
      if (l == 0) st_dword_sc(fown, (uint32_t)(t + 1));
    }
  }
}

// ---------------------------------------------------------------------------
extern "C" void kernel_launch(void* const* d_in, const int* in_sizes, int n_in,
                              void* d_out, int out_size, void* d_ws, size_t ws_size,
                              hipStream_t stream) {
  const float* x    = (const float*)d_in[0];
  const float* Wx   = (const float*)d_in[1];
  const float* Wh   = (const float*)d_in[2];
  const float* bias = (const float*)d_in[3];
  float* out = (float*)d_out;

  // ws layout (~8.3 MiB): split weights + bf16-h double buffer + flags
  char* ws = (char*)d_ws;
  uint16_t* wxt_hi = (uint16_t*)(ws);
  uint16_t* wxt_lo = (uint16_t*)(ws + (2u << 20));
  uint16_t* wht_hi = (uint16_t*)(ws + (4u << 20));
  uint16_t* wht_lo = (uint16_t*)(ws + (6u << 20));
  uint16_t* hq     = (uint16_t*)(ws + (8u << 20));               // 2 x 128 KB
  unsigned* flags  = (unsigned*)(ws + (8u << 20) + (1u << 18));  // 4 KB

  prep_kernel<<<dim3(2048), dim3(256), 0, stream>>>(Wx, Wh, wxt_hi, wxt_lo,
                                                    wht_hi, wht_lo, flags);
  xw_gemm_kernel<<<dim3(2048), dim3(256), 0, stream>>>(x, wxt_hi, wxt_lo, bias, out);
  rnn_seq_kernel<<<dim3(NBLK2), dim3(512), 0, stream>>>(out, wht_hi, wht_lo,
                                                        hq, flags);
}